// Round 5
// baseline (29.342 us; speedup 1.0000x reference)
//
#include <hip/hip_runtime.h>
#include <math.h>

#define NB 16          // batch
#define NT 512         // time
#define NC 32          // channels
#define NW 128         // window
#define TILE_T 32
#define NTILES (NT / TILE_T)        // 16
#define NBLK (NB * NTILES)          // 256 blocks -> one per CU
#define NROWS (TILE_T + NW)         // 160 rows staged per block
#define XT_S 164                    // x-tile stride (dwords): 16B-aligned, 164%32=4 -> minimal b128 aliasing
#define W_S  132                    // weight-table stride
#define WIN_MIN_F 2.0f
#define WIN_RANGE_F 62.0f

// ws layout (floats):
#define WS_FMEAN 0
#define WS_FSTD  (NB*NT*NC)
#define WS_PART  (2*NB*NT*NC)       // NBLK * 4 * NC

__device__ __forceinline__ float fast_sigmoid_neg(float a) {
    // sigmoid(-a) = 1/(1+exp(a))
    return __builtin_amdgcn_rcpf(1.0f + __expf(a));
}

__global__ __launch_bounds__(256) void feat_main(
    const float* __restrict__ series,
    const int*   __restrict__ indices,
    const float* __restrict__ rwm,
    const float* __restrict__ rws,
    float* __restrict__ f_mean,
    float* __restrict__ f_std,
    float* __restrict__ partials)
{
    __shared__ __align__(16) float s_xt [NC * XT_S];   // [c][row] transposed, 21 KB
    __shared__ __align__(16) float s_w1t[NC * W_S];    // [c][w], 16.9 KB
    __shared__ __align__(16) float s_w2t[NC * W_S];
    __shared__ float s_win[2 * NC];
    __shared__ float s_inv[2 * NC];
    __shared__ float s_red[4 * 8 * NC];

    const int tid = threadIdx.x;
    const int blk = blockIdx.x;
    const int b   = blk >> 4;
    const int tt  = blk & 15;
    const int t0  = tt * TILE_T;
    const int start = indices[2 * b];

    if (tid < 2 * NC) {
        const float raw = (tid < NC) ? rwm[tid] : rws[tid - NC];
        s_win[tid] = WIN_MIN_F + WIN_RANGE_F * fast_sigmoid_neg(-raw);
    }

    // ---- stage transposed: b128 global reads, scalar transposed LDS writes ----
    const float4* g4 = (const float4*)(series + (size_t)(start - NW + t0) * NC);
#pragma unroll
    for (int k = 0; k < 5; ++k) {
        const int j = tid + k * 256;           // < 1280 float4s (160 rows x 32c)
        const float4 v = g4[j];
        const int row = j >> 3, c4 = (j & 7) * 4;
        s_xt[(c4 + 0) * XT_S + row] = v.x;
        s_xt[(c4 + 1) * XT_S + row] = v.y;
        s_xt[(c4 + 2) * XT_S + row] = v.z;
        s_xt[(c4 + 3) * XT_S + row] = v.w;
    }
    __syncthreads();

    // ---- weight tables transposed: w[c][j] = 1/(1+exp(age - win[c])) ----
#pragma unroll
    for (int k = 0; k < 16; ++k) {
        const int i = tid + k * 256;           // < 4096
        const int w = i & 127, c = i >> 7;
        const float age = (float)(NW - 1 - w);
        s_w1t[c * W_S + w] = fast_sigmoid_neg(age - s_win[c]);
        s_w2t[c * W_S + w] = fast_sigmoid_neg(age - s_win[NC + c]);
    }
    __syncthreads();

    // ---- weight sums -> reciprocals (one wave) ----
    if (tid < 64) {
        const int c = tid & 31;
        const float* wt = ((tid < 32) ? s_w1t : s_w2t) + c * W_S;
        float sx = 0.f, sy = 0.f, sz = 0.f, sw = 0.f;
#pragma unroll
        for (int g = 0; g < 32; ++g) {
            const float4 v = *(const float4*)(wt + 4 * g);
            sx += v.x; sy += v.y; sz += v.z; sw += v.w;
        }
        s_inv[tid] = __builtin_amdgcn_rcpf((sx + sy) + (sz + sw));
    }
    __syncthreads();

    // ---- main loop: thread owns channel c, 4 rows; all LDS reads are b128 ----
    const int c  = tid & 31;
    const int tg = tid >> 5;               // 0..7
    const int rb = tg * 4;
    const float* xrow = s_xt  + c * XT_S + rb;
    const float* w1p  = s_w1t + c * W_S;
    const float* w2p  = s_w2t + c * W_S;

    float a1[4], a2[4], a3[4];
#pragma unroll
    for (int k = 0; k < 4; ++k) { a1[k] = 0.f; a2[k] = 0.f; a3[k] = 0.f; }

    float4 xa = *(const float4*)(xrow);    // rows rb..rb+3
    float4 qa; qa.x = xa.x*xa.x; qa.y = xa.y*xa.y; qa.z = xa.z*xa.z; qa.w = xa.w*xa.w;

#pragma unroll
    for (int g = 0; g < 32; ++g) {
        const float4 wv1 = *(const float4*)(w1p + 4 * g);
        const float4 wv2 = *(const float4*)(w2p + 4 * g);
        const float4 xb  = *(const float4*)(xrow + 4 * g + 4);   // next 4 rows (max row 159)
        float4 qb; qb.x = xb.x*xb.x; qb.y = xb.y*xb.y; qb.z = xb.z*xb.z; qb.w = xb.w*xb.w;

        const float xs[8] = {xa.x, xa.y, xa.z, xa.w, xb.x, xb.y, xb.z, xb.w};
        const float qs[8] = {qa.x, qa.y, qa.z, qa.w, qb.x, qb.y, qb.z, qb.w};
        const float w1a[4] = {wv1.x, wv1.y, wv1.z, wv1.w};
        const float w2a[4] = {wv2.x, wv2.y, wv2.z, wv2.w};

#pragma unroll
        for (int j = 0; j < 4; ++j) {
#pragma unroll
            for (int k = 0; k < 4; ++k) {
                a1[k] = fmaf(xs[j + k], w1a[j], a1[k]);
                a2[k] = fmaf(xs[j + k], w2a[j], a2[k]);
                a3[k] = fmaf(qs[j + k], w2a[j], a3[k]);
            }
        }
        xa = xb; qa = qb;
    }

    const float inv1 = s_inv[c];
    const float inv2 = s_inv[NC + c];

    float p0 = 0.f, p1 = 0.f, p2 = 0.f, p3 = 0.f;
#pragma unroll
    for (int k = 0; k < 4; ++k) {
        const float fm = a1[k] * inv1;
        const float m2 = a2[k] * inv2;
        float var = a3[k] * inv2 - m2 * m2;
        var = fmaxf(var, 0.0f);
        const float fs = sqrtf(var + 1e-8f);
        const int t = t0 + rb + k;
        const size_t o = ((size_t)b * NT + t) * NC + c;
        f_mean[o] = fm;
        f_std[o]  = fs;
        p0 += fm; p1 += fm * fm; p2 += fs; p3 += fs * fs;
    }

    s_red[(0 * 8 + tg) * NC + c] = p0;
    s_red[(1 * 8 + tg) * NC + c] = p1;
    s_red[(2 * 8 + tg) * NC + c] = p2;
    s_red[(3 * 8 + tg) * NC + c] = p3;
    __syncthreads();

    if (tid < 4 * NC) {
        const int a = tid >> 5, cc = tid & 31;
        float s = 0.f;
#pragma unroll
        for (int g = 0; g < 8; ++g) s += s_red[(a * 8 + g) * NC + cc];
        partials[blk * (4 * NC) + a * NC + cc] = s;
    }
}

// BN-reduce (redundant per block) + writeout. 256 blocks x 192 threads, 32 rows each.
__global__ __launch_bounds__(192) void bn_write(
    const float* __restrict__ x,
    const float* __restrict__ f_mean,
    const float* __restrict__ f_std,
    const float* __restrict__ partials,
    const float* __restrict__ gm, const float* __restrict__ bm,
    const float* __restrict__ gs, const float* __restrict__ bs,
    float* __restrict__ out)
{
    __shared__ __align__(16) float s_part[6 * 128];   // 6 slices x 128 cells
    __shared__ __align__(16) float s_sums[128];       // [a][c]
    __shared__ __align__(16) float s_coef[4 * NC];    // A1,B1,A2,B2

    const int tid = threadIdx.x;

    // phase 1: reduce partials [256][128] as float4 cells, 6-way slice split
    {
        const int cell  = tid & 31;        // float4 cell
        const int slice = tid >> 5;        // 0..5
        const int bb0 = slice * 43;
        const int bb1 = (bb0 + 43 > NBLK) ? NBLK : bb0 + 43;
        const float4* p4 = (const float4*)partials;
        float4 acc = {0.f, 0.f, 0.f, 0.f};
        for (int bb = bb0; bb < bb1; ++bb) {
            const float4 v = p4[bb * 32 + cell];
            acc.x += v.x; acc.y += v.y; acc.z += v.z; acc.w += v.w;
        }
        *(float4*)&s_part[(slice * 32 + cell) * 4] = acc;
    }
    __syncthreads();
    if (tid < 32) {
        float4 s = {0.f, 0.f, 0.f, 0.f};
#pragma unroll
        for (int sl = 0; sl < 6; ++sl) {
            const float4 v = ((const float4*)s_part)[sl * 32 + tid];
            s.x += v.x; s.y += v.y; s.z += v.z; s.w += v.w;
        }
        ((float4*)s_sums)[tid] = s;
    }
    __syncthreads();
    if (tid < NC) {
        const float invN = 1.0f / (float)(NB * NT);
        const float mu_m  = s_sums[tid] * invN;
        float var_m = s_sums[32 + tid] * invN - mu_m * mu_m;
        var_m = fmaxf(var_m, 0.0f);
        const float A1 = gm[tid] / sqrtf(var_m + 1e-5f);
        const float B1 = bm[tid] - mu_m * A1;
        const float mu_s  = s_sums[64 + tid] * invN;
        float var_s = s_sums[96 + tid] * invN - mu_s * mu_s;
        var_s = fmaxf(var_s, 0.0f);
        const float A2 = gs[tid] / sqrtf(var_s + 1e-5f);
        const float B2 = bs[tid] - mu_s * A2;
        s_coef[tid]          = A1;
        s_coef[NC + tid]     = B1;
        s_coef[2 * NC + tid] = A2;
        s_coef[3 * NC + tid] = B2;
    }
    __syncthreads();

    // phase 2: writeout 32 rows (24 float4s per out row)
    const float4* x4  = (const float4*)x;
    const float4* fm4 = (const float4*)f_mean;
    const float4* fs4 = (const float4*)f_std;
    const float4* cf4 = (const float4*)s_coef;   // [0..7]=A1 [8..15]=B1 [16..23]=A2 [24..31]=B2
    float4* out4 = (float4*)out;
    const int row0 = blockIdx.x * 32;

#pragma unroll
    for (int k = 0; k < 4; ++k) {
        const int idx = tid + k * 192;           // < 768 = 32 rows * 24
        const int r = idx / 24;
        const int q = idx - r * 24;
        const int row = row0 + r;
        float4 v;
        if (q < 8) {
            v = x4[row * 8 + q];
        } else if (q < 16) {
            const int m = q - 8;
            const float4 f = fm4[row * 8 + m];
            const float4 A = cf4[m], Bv = cf4[8 + m];
            v.x = fmaf(f.x, A.x, Bv.x); v.y = fmaf(f.y, A.y, Bv.y);
            v.z = fmaf(f.z, A.z, Bv.z); v.w = fmaf(f.w, A.w, Bv.w);
        } else {
            const int m = q - 16;
            const float4 f = fs4[row * 8 + m];
            const float4 A = cf4[16 + m], Bv = cf4[24 + m];
            v.x = fmaf(f.x, A.x, Bv.x); v.y = fmaf(f.y, A.y, Bv.y);
            v.z = fmaf(f.z, A.z, Bv.z); v.w = fmaf(f.w, A.w, Bv.w);
        }
        out4[row * 24 + q] = v;
    }
}

extern "C" void kernel_launch(void* const* d_in, const int* in_sizes, int n_in,
                              void* d_out, int out_size, void* d_ws, size_t ws_size,
                              hipStream_t stream) {
    const float* x      = (const float*)d_in[0];
    const float* series = (const float*)d_in[1];
    const int*   idx    = (const int*)d_in[2];
    const float* rwm    = (const float*)d_in[3];
    const float* rws    = (const float*)d_in[4];
    const float* gm     = (const float*)d_in[5];
    const float* bm     = (const float*)d_in[6];
    const float* gs     = (const float*)d_in[7];
    const float* bs     = (const float*)d_in[8];
    float* out = (float*)d_out;
    float* ws  = (float*)d_ws;

    float* f_mean   = ws + WS_FMEAN;
    float* f_std    = ws + WS_FSTD;
    float* partials = ws + WS_PART;

    feat_main<<<NBLK, 256, 0, stream>>>(series, idx, rwm, rws, f_mean, f_std, partials);
    bn_write<<<NBLK, 192, 0, stream>>>(x, f_mean, f_std, partials, gm, bm, gs, bs, out);
}